// Round 15
// baseline (234.790 us; speedup 1.0000x reference)
//
#include <hip/hip_runtime.h>

#define NS   262144
#define NN   24
#define CI   32
#define HW   32
#define SPB  8                     // samples per tile (24KB f32)
#define NBLK 512                   // persistent: 2 blocks per CU
#define TPB  (NS / SPB / NBLK)     // 64 tiles per block

typedef __fp16 fp16x2v __attribute__((ext_vector_type(2)));
typedef _Float16 half8 __attribute__((ext_vector_type(8)));
typedef float f32x4 __attribute__((ext_vector_type(4)));
typedef unsigned int u32x4 __attribute__((ext_vector_type(4)));

// f16 fragments of W1^T used as the MFMA *A* operand (verified R2-R14):
// g_w1f[n][half][lane][i] = W1[n][c=(lane>>4)*8+i][w=half*16+(lane&15)]
__device__ alignas(16) unsigned short g_w1f[NN * 2 * 64 * 8];

__global__ void pack_w1(const float* __restrict__ W1) {
  int idx = blockIdx.x * 256 + threadIdx.x;
  if (idx >= NN * 2 * 64 * 8) return;
  int i    = idx & 7;
  int lane = (idx >> 3) & 63;
  int hf   = (idx >> 9) & 1;
  int n    = idx >> 10;
  int k = (lane >> 4) * 8 + i;
  int w = hf * 16 + (lane & 15);
  _Float16 v = (_Float16)W1[(n * CI + k) * HW + w];
  g_w1f[idx] = __builtin_bit_cast(unsigned short, v);
}

__device__ __forceinline__ unsigned pkrtz(float a, float b) {
  fp16x2v p = __builtin_amdgcn_cvt_pkrtz(a, b);
  return __builtin_bit_cast(unsigned, p);
}

__device__ __forceinline__ void gload16(const float* g, float* l) {
  __builtin_amdgcn_global_load_lds(
      (const __attribute__((address_space(1))) void*)g,
      (__attribute__((address_space(3))) void*)l, 16, 0, 0);
}

// 2 independent sync domains per CU: each block has its own counted-vmcnt
// pipeline; their phase offset covers each other's barrier-jitter stalls.
__global__ __launch_bounds__(512, 4) void mlp_mfma(
    const float* __restrict__ h, const int* __restrict__ valid,
    const float* __restrict__ b1, const float* __restrict__ W2,
    const float* __restrict__ b2, float* __restrict__ out) {
  __shared__ alignas(16) float buf[3][SPB * NN * CI];   // 3 x 24KB
  __shared__ float sb1[NN * HW], sw2[NN * HW], sb2v[NN]; // ~6KB  (78KB total)

  const int tid  = threadIdx.x;
  const int lane = tid & 63;
  const int wv   = tid >> 6;     // 0..7
  const int r    = lane & 15;    // B col = sample; A row = hidden w
  const int q    = lane >> 4;    // k-chunk group; C row-group
  const int r8   = r & 7;        // physical sample row (r>=8 duplicates)

  {  // tables (threads with t4<768 load BOTH quads — R10 lesson)
    const int t4 = tid * 4;
    if (t4 < NN * HW) {
      *(f32x4*)&sb1[t4] = *(const f32x4*)&b1[t4];
      *(f32x4*)&sw2[t4] = *(const f32x4*)&W2[t4];
    }
    if (tid < NN) sb2v[tid] = b2[tid];
  }

  // Register-resident W1 fragments: this wave's 3 nodes
  half8 Af0[3], Af1[3];
#pragma unroll
  for (int ni = 0; ni < 3; ++ni) {
    const int n = wv * 3 + ni;
    Af0[ni] = __builtin_bit_cast(half8,
        *(const u32x4*)&g_w1f[((n * 2 + 0) * 64 + lane) * 8]);
    Af1[ni] = __builtin_bit_cast(half8,
        *(const u32x4*)&g_w1f[((n * 2 + 1) * 64 + lane) * 8]);
  }

  const int tile0 = blockIdx.x * TPB;

  // Stage one 24KB tile: 3 rounds x 512 thr x 16B. Run k2=rd*8+wv covers
  // chunks [64k2,64k2+64) within one row-third (192=3*64) -> row s=k2/3
  // wave-uniform (DMA-legal). Source pre-swizzled ^((s&7)<<4).
#define STAGE(tile, dst)                                                      \
  do {                                                                        \
    const float* gt = h + (size_t)(tile) * (SPB * NN * CI);                   \
    _Pragma("unroll") for (int rd = 0; rd < 3; ++rd) {                        \
      const int k2 = rd * 8 + wv;                                             \
      const int s  = k2 / 3, third = k2 % 3;                                  \
      const int dstf = (k2 * 64 + lane) * 4;                                  \
      const int srcb = ((third * 64 + lane) * 16) ^ ((s & 7) << 4);           \
      gload16(gt + s * 768 + (srcb >> 2), (dst) + dstf);                      \
    }                                                                         \
  } while (0)

  // ds_read base: physical row r8; swizzled chunk bits; +n*128 per node.
  // 8 rows x XOR-spread -> all 32 banks covered; lanes r and r+8 broadcast.
  const int aA = r8 * 3072 + ((q * 32) ^ (r8 << 4));
  const int aB = aA ^ 16;

#define COMPUTE(t, src)                                                       \
  do {                                                                        \
    const char* cb = (const char*)(src);                                      \
    const int srow = (tile0 + (t)) * SPB + r8;                                \
    _Pragma("unroll") for (int ni = 0; ni < 3; ++ni) {                        \
      const int n = wv * 3 + ni;                                              \
      f32x4 d0 = *(const f32x4*)(cb + aA + n * 128);                          \
      f32x4 d1 = *(const f32x4*)(cb + aB + n * 128);                          \
      const int vld = valid[srow * NN + n];                                   \
      u32x4 uu;                                                               \
      uu[0] = pkrtz(fmaxf(d0[0], 0.f), fmaxf(d0[1], 0.f));                    \
      uu[1] = pkrtz(fmaxf(d0[2], 0.f), fmaxf(d0[3], 0.f));                    \
      uu[2] = pkrtz(fmaxf(d1[0], 0.f), fmaxf(d1[1], 0.f));                    \
      uu[3] = pkrtz(fmaxf(d1[2], 0.f), fmaxf(d1[3], 0.f));                    \
      half8 Hf = __builtin_bit_cast(half8, uu);                               \
      f32x4 b1a = *(const f32x4*)&sb1[n * HW + q * 4];                        \
      f32x4 b1b = *(const f32x4*)&sb1[n * HW + 16 + q * 4];                   \
      f32x4 w2a = *(const f32x4*)&sw2[n * HW + q * 4];                        \
      f32x4 w2b = *(const f32x4*)&sw2[n * HW + 16 + q * 4];                   \
      f32x4 c0 = {b1a[0], b1a[1], b1a[2], b1a[3]};                            \
      f32x4 c1 = {b1b[0], b1b[1], b1b[2], b1b[3]};                            \
      c0 = __builtin_amdgcn_mfma_f32_16x16x32_f16(Af0[ni], Hf, c0, 0, 0, 0);  \
      c1 = __builtin_amdgcn_mfma_f32_16x16x32_f16(Af1[ni], Hf, c1, 0, 0, 0);  \
      float p = 0.f;                                                          \
      _Pragma("unroll") for (int i = 0; i < 4; ++i) {                         \
        p = fmaf(fmaxf(c0[i], 0.f), w2a[i], p);                               \
        p = fmaf(fmaxf(c1[i], 0.f), w2b[i], p);                               \
      }                                                                       \
      p += __shfl_xor(p, 16);                                                 \
      p += __shfl_xor(p, 32);                                                 \
      if (lane < 8)  /* q==0 && r<8: lane owns sample srow */                 \
        out[(size_t)srow * NN + n] = vld ? (p + sb2v[n]) : 0.0f;              \
    }                                                                         \
  } while (0)

  __syncthreads();   // tables resident; vmem count clean

  STAGE(tile0 + 0, buf[0]);
  STAGE(tile0 + 1, buf[1]);
  asm volatile("s_waitcnt vmcnt(3)" ::: "memory");   // tile0 landed
  __builtin_amdgcn_sched_barrier(0);
  __builtin_amdgcn_s_barrier();

  for (int t = 0; t < TPB - 2; ++t) {
    COMPUTE(t, buf[t % 3]);                 // epilogue vmem >= 2 ops
    STAGE(tile0 + t + 2, buf[(t + 2) % 3]); // 3 ops
    asm volatile("s_waitcnt vmcnt(5)" ::: "memory");  // tile t+1 landed
    __builtin_amdgcn_sched_barrier(0);
    __builtin_amdgcn_s_barrier();
  }

  COMPUTE(TPB - 2, buf[(TPB - 2) % 3]);
  asm volatile("s_waitcnt vmcnt(2)" ::: "memory");    // tile TPB-1 landed
  __builtin_amdgcn_sched_barrier(0);
  __builtin_amdgcn_s_barrier();
  COMPUTE(TPB - 1, buf[(TPB - 1) % 3]);

#undef STAGE
#undef COMPUTE
}

extern "C" void kernel_launch(void* const* d_in, const int* in_sizes, int n_in,
                              void* d_out, int out_size, void* d_ws, size_t ws_size,
                              hipStream_t stream) {
  const float* h     = (const float*)d_in[0];
  const int*   valid = (const int*)d_in[1];
  const float* W1    = (const float*)d_in[2];
  const float* b1    = (const float*)d_in[3];
  const float* W2    = (const float*)d_in[4];
  const float* b2    = (const float*)d_in[5];
  float* out = (float*)d_out;

  hipLaunchKernelGGL(pack_w1, dim3((NN * 2 * 64 * 8 + 255) / 256), dim3(256),
                     0, stream, W1);
  hipLaunchKernelGGL(mlp_mfma, dim3(NBLK), dim3(512), 0, stream,
                     h, valid, b1, W2, b2, out);
}